// Round 1
// baseline (2137.386 us; speedup 1.0000x reference)
//
#include <hip/hip_runtime.h>

// ProbSparse attention, round 1: all-fp32 correctness-first implementation.
// B=4, L=S=4096, D_MODEL=1024, H=16, D_K=64, SAMPLE_K=N_TOP=40, SCALE=1/8.
//
// Pipeline:
//   1. transpose1024: WoT = Wo^T (for coalesced scatter reads)
//   2. proj_gemm x3 : Q/K/V = x @ W^T + b, written as [b*h][l][64] (fp32 NT-GEMM)
//   3. sample_scores: M[bh][l] = max_s(q.k_samp) - mean_s(q.k_samp)   (40 samples)
//   4. topk40       : per (b,h) top-40 indices of M (exact, iterative argmax)
//   5. init_out     : out[b][l][:] = bo
//   6. flash_attn   : split-K online-softmax attention for the 40 selected rows
//   7. combine_ctx  : merge split partials -> context rows
//   8. scatter_out  : out[b][l_top] += ctx @ Wo_slice^T  (fp32 atomics)

#define NTOP 40
#define NSAMP 40
#define SCALE 0.125f
#define SPLIT 16
#define KEYS_PER_SPLIT 256   // 4096 / SPLIT

// workspace offsets (in floats)
#define Q_OFF    0ull
#define K_OFF    16777216ull
#define V_OFF    33554432ull
#define M_OFF    50331648ull   // 262144 floats
#define MTOP_OFF 50593792ull   // 2560 ints (reserve 4096)
#define WOT_OFF  50597888ull   // 1048576 floats
#define CTXP_OFF 51646464ull   // 16*64*64*64 = 4194304 floats
#define MLP_OFF  55840768ull   // 16*64*64*2  = 131072 floats
#define CTX_OFF  55971840ull   // 64*40*64    = 163840 floats
// total = 56135680 floats = 224.5 MB of d_ws

// ---------------------------------------------------------------- transpose
__global__ __launch_bounds__(256) void transpose1024(
    const float* __restrict__ A, float* __restrict__ AT) {
  __shared__ float tile[64][68];
  const int t = threadIdx.x;
  const int x0 = blockIdx.x * 64;
  const int y0 = blockIdx.y * 64;
  const int tr = t >> 4;
  const int tc = (t & 15) * 4;
#pragma unroll
  for (int i = 0; i < 4; ++i) {
    int r = tr + i * 16;
    float4 v = *(const float4*)&A[(size_t)(y0 + r) * 1024 + x0 + tc];
    *(float4*)&tile[r][tc] = v;
  }
  __syncthreads();
#pragma unroll
  for (int i = 0; i < 4; ++i) {
    int r = tr + i * 16;  // row in AT = col in A
    float4 v;
    v.x = tile[tc + 0][r];
    v.y = tile[tc + 1][r];
    v.z = tile[tc + 2][r];
    v.w = tile[tc + 3][r];
    *(float4*)&AT[(size_t)(x0 + r) * 1024 + y0 + tc] = v;
  }
}

// ---------------------------------------------------------------- projection GEMM
// C[m][n] = sum_k X[m][k] * W[n][k] + bias[n], M=16384, N=K=1024.
// Output permuted to [b*16+h][l][d] (h = n/64, d = n%64, b = m/4096, l = m%4096).
// BM=BN=128, BK=16, 256 threads, 8x8 acc/thread, k-major LDS tiles (pad 132).
__global__ __launch_bounds__(256) void proj_gemm(
    const float* __restrict__ X, const float* __restrict__ W,
    const float* __restrict__ bias, float* __restrict__ Out) {
  __shared__ float As[16][132];
  __shared__ float Bs[16][132];
  const int t = threadIdx.x;
  const int m0 = blockIdx.x * 128;
  const int n0 = blockIdx.y * 128;
  const int tm = t & 15, tn = t >> 4;
  float acc[8][8];
#pragma unroll
  for (int i = 0; i < 8; ++i)
#pragma unroll
    for (int j = 0; j < 8; ++j) acc[i][j] = 0.f;

  for (int k0 = 0; k0 < 1024; k0 += 16) {
#pragma unroll
    for (int p = 0; p < 2; ++p) {
      int idx = p * 256 + t;       // 512 float4s per tile
      int row = idx >> 2;          // 0..127
      int kq = (idx & 3) << 2;     // 0,4,8,12
      float4 av = *(const float4*)&X[(size_t)(m0 + row) * 1024 + k0 + kq];
      As[kq + 0][row] = av.x; As[kq + 1][row] = av.y;
      As[kq + 2][row] = av.z; As[kq + 3][row] = av.w;
      float4 bv = *(const float4*)&W[(size_t)(n0 + row) * 1024 + k0 + kq];
      Bs[kq + 0][row] = bv.x; Bs[kq + 1][row] = bv.y;
      Bs[kq + 2][row] = bv.z; Bs[kq + 3][row] = bv.w;
    }
    __syncthreads();
#pragma unroll
    for (int kk = 0; kk < 16; ++kk) {
      float4 a0 = *(const float4*)&As[kk][tm * 8];
      float4 a1 = *(const float4*)&As[kk][tm * 8 + 4];
      float4 b0 = *(const float4*)&Bs[kk][tn * 8];
      float4 b1 = *(const float4*)&Bs[kk][tn * 8 + 4];
      float a[8] = {a0.x, a0.y, a0.z, a0.w, a1.x, a1.y, a1.z, a1.w};
      float b[8] = {b0.x, b0.y, b0.z, b0.w, b1.x, b1.y, b1.z, b1.w};
#pragma unroll
      for (int i = 0; i < 8; ++i)
#pragma unroll
        for (int j = 0; j < 8; ++j) acc[i][j] = fmaf(a[i], b[j], acc[i][j]);
    }
    __syncthreads();
  }
#pragma unroll
  for (int i = 0; i < 8; ++i) {
    int gm = m0 + tm * 8 + i;
    int b = gm >> 12;
    int l = gm & 4095;
#pragma unroll
    for (int j4 = 0; j4 < 2; ++j4) {
      int n = n0 + tn * 8 + j4 * 4;
      float4 bb = *(const float4*)&bias[n];
      float4 r;
      r.x = acc[i][j4 * 4 + 0] + bb.x;
      r.y = acc[i][j4 * 4 + 1] + bb.y;
      r.z = acc[i][j4 * 4 + 2] + bb.z;
      r.w = acc[i][j4 * 4 + 3] + bb.w;
      int h = n >> 6, d = n & 63;
      *(float4*)&Out[(((size_t)(b * 16 + h)) * 4096 + l) * 64 + d] = r;
    }
  }
}

// ---------------------------------------------------------------- sample scores
__global__ __launch_bounds__(256) void sample_scores(
    const float* __restrict__ Q, const float* __restrict__ K,
    const int* __restrict__ samp, float* __restrict__ M) {
  __shared__ float Ks[NSAMP * 64];
  const int bh = blockIdx.y;
  const int t = threadIdx.x;
#pragma unroll
  for (int i = 0; i < 10; ++i) {
    int e = i * 256 + t;          // 2560 = 40*64
    int s = e >> 6, d = e & 63;
    Ks[e] = K[((size_t)bh * 4096 + samp[s]) * 64 + d];
  }
  __syncthreads();
  const int l = blockIdx.x * 256 + t;
  const float* qp = &Q[((size_t)bh * 4096 + l) * 64];
  float4 q[16];
#pragma unroll
  for (int i = 0; i < 16; ++i) q[i] = *(const float4*)&qp[i * 4];
  float mx = -1e30f, sum = 0.f;
#pragma unroll
  for (int s = 0; s < NSAMP; ++s) {
    float acc = 0.f;
#pragma unroll
    for (int i = 0; i < 16; ++i) {
      float4 kv = *(const float4*)&Ks[s * 64 + i * 4];
      acc = fmaf(q[i].x, kv.x, acc);
      acc = fmaf(q[i].y, kv.y, acc);
      acc = fmaf(q[i].z, kv.z, acc);
      acc = fmaf(q[i].w, kv.w, acc);
    }
    mx = fmaxf(mx, acc);
    sum += acc;
  }
  M[(size_t)bh * 4096 + l] = mx - sum * (1.f / 40.f);
}

// ---------------------------------------------------------------- top-40
__global__ __launch_bounds__(256) void topk40(
    const float* __restrict__ M, int* __restrict__ Mtop) {
  __shared__ unsigned long long keys[4096];
  __shared__ unsigned long long red[256];
  const int bh = blockIdx.x;
  const int t = threadIdx.x;
#pragma unroll
  for (int i = 0; i < 16; ++i) {
    int idx = i * 256 + t;
    float f = M[(size_t)bh * 4096 + idx];
    unsigned int u = __float_as_uint(f);
    u = (u & 0x80000000u) ? ~u : (u | 0x80000000u);   // total order map
    keys[idx] = (((unsigned long long)u) << 32) | (unsigned long long)(4095 - idx);
  }
  __syncthreads();
  for (int it = 0; it < NTOP; ++it) {
    unsigned long long best = 0;
#pragma unroll
    for (int i = 0; i < 16; ++i) {
      unsigned long long v = keys[i * 256 + t];
      best = v > best ? v : best;
    }
    red[t] = best;
    __syncthreads();
    for (int s = 128; s > 0; s >>= 1) {
      if (t < s) {
        unsigned long long o = red[t + s];
        if (o > red[t]) red[t] = o;
      }
      __syncthreads();
    }
    int idx = 4095 - (int)(red[0] & 0xFFFFFFFFull);
    if (t == 0) {
      Mtop[bh * NTOP + it] = idx;
      keys[idx] = 0;
    }
    __syncthreads();
  }
}

// ---------------------------------------------------------------- bias init
__global__ __launch_bounds__(256) void init_out(
    const float* __restrict__ bo, float* __restrict__ out) {
  const int t = threadIdx.x;
  const float4* bo4 = (const float4*)bo;
  float4* o4 = (float4*)out;
#pragma unroll
  for (int rep = 0; rep < 4; ++rep) {
    size_t idx = (size_t)rep * 1048576 + (size_t)blockIdx.x * 256 + t;
    o4[idx] = bo4[idx & 255];   // 1024 floats = 256 float4 per row
  }
}

// ---------------------------------------------------------------- flash attention
// grid (SPLIT, 64). Block: 4 waves. Phase A: wave w computes scores for rows
// [16w,16w+16) x 64 keys (K row in lane regs, Q broadcast from LDS), writes
// S^T to LDS stride 65 (conflict-free). Phase B: lane r = t&63 owns a row,
// wave owns d-slice of 16; online softmax + PV with V broadcast loads.
__global__ __launch_bounds__(256) void flash_attn(
    const float* __restrict__ Q, const float* __restrict__ K,
    const float* __restrict__ V, const int* __restrict__ Mtop,
    float* __restrict__ ctx_part, float* __restrict__ ml_part) {
  __shared__ float Qs[64 * 64];
  __shared__ float Sb[64 * 65];
  __shared__ int topIdx[64];
  const int t = threadIdx.x;
  const int lane = t & 63;
  const int w = t >> 6;
  const int split = blockIdx.x;
  const int bh = blockIdx.y;
  if (t < 64) topIdx[t] = (t < NTOP) ? Mtop[bh * NTOP + t] : 0;
  __syncthreads();
#pragma unroll
  for (int i = 0; i < 4; ++i) {
    int e = i * 1024 + t * 4;
    int r = e >> 6, d = e & 63;
    float4 val = make_float4(0.f, 0.f, 0.f, 0.f);
    if (r < NTOP)
      val = *(const float4*)&Q[(((size_t)bh) * 4096 + topIdx[r]) * 64 + d];
    *(float4*)&Qs[e] = val;
  }
  float m_r = -1e30f, l_r = 0.f;
  float4 acc0 = make_float4(0.f, 0.f, 0.f, 0.f);
  float4 acc1 = acc0, acc2 = acc0, acc3 = acc0;
  const float* Kb = K + (size_t)bh * 4096 * 64;
  const float* Vb = V + (size_t)bh * 4096 * 64;
  const int key0 = split * KEYS_PER_SPLIT;
  const int d0 = w * 16;
  __syncthreads();

  for (int c = 0; c < KEYS_PER_SPLIT / 64; ++c) {
    const int j = key0 + c * 64 + lane;
    float4 kr[16];
#pragma unroll
    for (int i = 0; i < 16; ++i)
      kr[i] = *(const float4*)&Kb[(size_t)j * 64 + i * 4];
    const int rbase = w * 16;
#pragma unroll
    for (int rr = 0; rr < 16; ++rr) {
      const float* qrow = &Qs[(rbase + rr) * 64];
      float s = 0.f;
#pragma unroll
      for (int i = 0; i < 16; ++i) {
        float4 q4 = *(const float4*)&qrow[i * 4];
        s = fmaf(q4.x, kr[i].x, s);
        s = fmaf(q4.y, kr[i].y, s);
        s = fmaf(q4.z, kr[i].z, s);
        s = fmaf(q4.w, kr[i].w, s);
      }
      Sb[lane * 65 + rbase + rr] = s * SCALE;
    }
    __syncthreads();
    // phase B: lane = row
    float sv[64];
    float cm = -1e30f;
#pragma unroll
    for (int j2 = 0; j2 < 64; ++j2) {
      sv[j2] = Sb[j2 * 65 + lane];
      cm = fmaxf(cm, sv[j2]);
    }
    float nm = fmaxf(m_r, cm);
    float alpha = __expf(m_r - nm);
    m_r = nm;
    l_r *= alpha;
    acc0.x *= alpha; acc0.y *= alpha; acc0.z *= alpha; acc0.w *= alpha;
    acc1.x *= alpha; acc1.y *= alpha; acc1.z *= alpha; acc1.w *= alpha;
    acc2.x *= alpha; acc2.y *= alpha; acc2.z *= alpha; acc2.w *= alpha;
    acc3.x *= alpha; acc3.y *= alpha; acc3.z *= alpha; acc3.w *= alpha;
#pragma unroll
    for (int j2 = 0; j2 < 64; ++j2) {
      float p = __expf(sv[j2] - nm);
      l_r += p;
      const float* vrow = &Vb[(size_t)(key0 + c * 64 + j2) * 64 + d0];
      float4 v0 = *(const float4*)&vrow[0];
      float4 v1 = *(const float4*)&vrow[4];
      float4 v2 = *(const float4*)&vrow[8];
      float4 v3 = *(const float4*)&vrow[12];
      acc0.x = fmaf(p, v0.x, acc0.x); acc0.y = fmaf(p, v0.y, acc0.y);
      acc0.z = fmaf(p, v0.z, acc0.z); acc0.w = fmaf(p, v0.w, acc0.w);
      acc1.x = fmaf(p, v1.x, acc1.x); acc1.y = fmaf(p, v1.y, acc1.y);
      acc1.z = fmaf(p, v1.z, acc1.z); acc1.w = fmaf(p, v1.w, acc1.w);
      acc2.x = fmaf(p, v2.x, acc2.x); acc2.y = fmaf(p, v2.y, acc2.y);
      acc2.z = fmaf(p, v2.z, acc2.z); acc2.w = fmaf(p, v2.w, acc2.w);
      acc3.x = fmaf(p, v3.x, acc3.x); acc3.y = fmaf(p, v3.y, acc3.y);
      acc3.z = fmaf(p, v3.z, acc3.z); acc3.w = fmaf(p, v3.w, acc3.w);
    }
    __syncthreads();
  }
  size_t pbase = (((size_t)split * 64 + bh) * 64 + lane) * 64 + d0;
  *(float4*)&ctx_part[pbase + 0] = acc0;
  *(float4*)&ctx_part[pbase + 4] = acc1;
  *(float4*)&ctx_part[pbase + 8] = acc2;
  *(float4*)&ctx_part[pbase + 12] = acc3;
  if (w == 0) {
    size_t mb = (((size_t)split * 64 + bh) * 64 + lane) * 2;
    ml_part[mb + 0] = m_r;
    ml_part[mb + 1] = l_r;
  }
}

// ---------------------------------------------------------------- combine splits
__global__ __launch_bounds__(256) void combine_ctx(
    const float* __restrict__ ctx_part, const float* __restrict__ ml_part,
    float* __restrict__ ctx) {
  const int bh = blockIdx.x;
  const int t = threadIdx.x;
  const int r = t & 63;
  const int dg = t >> 6;
  if (r >= NTOP) return;
  float mt = -1e30f;
#pragma unroll
  for (int s = 0; s < SPLIT; ++s)
    mt = fmaxf(mt, ml_part[(((size_t)s * 64 + bh) * 64 + r) * 2]);
  float Lt = 0.f;
  float4 a0 = make_float4(0.f, 0.f, 0.f, 0.f);
  float4 a1 = a0, a2 = a0, a3 = a0;
  const int d0 = dg * 16;
#pragma unroll
  for (int s = 0; s < SPLIT; ++s) {
    size_t mb = (((size_t)s * 64 + bh) * 64 + r) * 2;
    float ms = ml_part[mb], ls = ml_part[mb + 1];
    float wgt = __expf(ms - mt);
    Lt = fmaf(wgt, ls, Lt);
    size_t pb = (((size_t)s * 64 + bh) * 64 + r) * 64 + d0;
    float4 c0 = *(const float4*)&ctx_part[pb + 0];
    float4 c1 = *(const float4*)&ctx_part[pb + 4];
    float4 c2 = *(const float4*)&ctx_part[pb + 8];
    float4 c3 = *(const float4*)&ctx_part[pb + 12];
    a0.x = fmaf(wgt, c0.x, a0.x); a0.y = fmaf(wgt, c0.y, a0.y);
    a0.z = fmaf(wgt, c0.z, a0.z); a0.w = fmaf(wgt, c0.w, a0.w);
    a1.x = fmaf(wgt, c1.x, a1.x); a1.y = fmaf(wgt, c1.y, a1.y);
    a1.z = fmaf(wgt, c1.z, a1.z); a1.w = fmaf(wgt, c1.w, a1.w);
    a2.x = fmaf(wgt, c2.x, a2.x); a2.y = fmaf(wgt, c2.y, a2.y);
    a2.z = fmaf(wgt, c2.z, a2.z); a2.w = fmaf(wgt, c2.w, a2.w);
    a3.x = fmaf(wgt, c3.x, a3.x); a3.y = fmaf(wgt, c3.y, a3.y);
    a3.z = fmaf(wgt, c3.z, a3.z); a3.w = fmaf(wgt, c3.w, a3.w);
  }
  float inv = 1.f / Lt;
  size_t ob = ((size_t)bh * NTOP + r) * 64 + d0;
  a0.x *= inv; a0.y *= inv; a0.z *= inv; a0.w *= inv;
  a1.x *= inv; a1.y *= inv; a1.z *= inv; a1.w *= inv;
  a2.x *= inv; a2.y *= inv; a2.z *= inv; a2.w *= inv;
  a3.x *= inv; a3.y *= inv; a3.z *= inv; a3.w *= inv;
  *(float4*)&ctx[ob + 0] = a0;
  *(float4*)&ctx[ob + 4] = a1;
  *(float4*)&ctx[ob + 8] = a2;
  *(float4*)&ctx[ob + 12] = a3;
}

// ---------------------------------------------------------------- sparse out proj
__global__ __launch_bounds__(256) void scatter_out(
    const float* __restrict__ ctx, const int* __restrict__ Mtop,
    const float* __restrict__ WoT, float* __restrict__ out) {
  const int bx = blockIdx.x;  // 0..2559 = bh*40 + r
  const int bh = bx / NTOP;
  const int r = bx % NTOP;
  const int b = bh >> 4, h = bh & 15;
  const int t = threadIdx.x;
  __shared__ float crow[64];
  if (t < 16)
    *(float4*)&crow[t * 4] =
        *(const float4*)&ctx[((size_t)bh * NTOP + r) * 64 + t * 4];
  const int l = Mtop[bh * NTOP + r];
  __syncthreads();
  const int n0 = t * 4;
  float4 a = make_float4(0.f, 0.f, 0.f, 0.f);
#pragma unroll
  for (int d = 0; d < 64; ++d) {
    float cv = crow[d];
    float4 wv = *(const float4*)&WoT[(size_t)(h * 64 + d) * 1024 + n0];
    a.x = fmaf(cv, wv.x, a.x);
    a.y = fmaf(cv, wv.y, a.y);
    a.z = fmaf(cv, wv.z, a.z);
    a.w = fmaf(cv, wv.w, a.w);
  }
  float* orow = out + ((size_t)b * 4096 + l) * 1024 + n0;
  atomicAdd(&orow[0], a.x);
  atomicAdd(&orow[1], a.y);
  atomicAdd(&orow[2], a.z);
  atomicAdd(&orow[3], a.w);
}

// ---------------------------------------------------------------- launch
extern "C" void kernel_launch(void* const* d_in, const int* in_sizes, int n_in,
                              void* d_out, int out_size, void* d_ws, size_t ws_size,
                              hipStream_t stream) {
  const float* queries = (const float*)d_in[0];
  const float* keys    = (const float*)d_in[1];
  const float* values  = (const float*)d_in[2];
  const float* Wq = (const float*)d_in[3];
  const float* bq = (const float*)d_in[4];
  const float* Wk = (const float*)d_in[5];
  const float* bk = (const float*)d_in[6];
  const float* Wv = (const float*)d_in[7];
  const float* bv = (const float*)d_in[8];
  const float* Wo = (const float*)d_in[9];
  const float* bo = (const float*)d_in[10];
  const int* samp = (const int*)d_in[11];
  float* out = (float*)d_out;
  float* ws = (float*)d_ws;

  float* Qw   = ws + Q_OFF;
  float* Kw   = ws + K_OFF;
  float* Vw   = ws + V_OFF;
  float* Mws  = ws + M_OFF;
  int*   Mtop = (int*)(ws + MTOP_OFF);
  float* WoT  = ws + WOT_OFF;
  float* ctxp = ws + CTXP_OFF;
  float* mlp  = ws + MLP_OFF;
  float* ctxf = ws + CTX_OFF;

  transpose1024<<<dim3(16, 16), 256, 0, stream>>>(Wo, WoT);
  proj_gemm<<<dim3(128, 8), 256, 0, stream>>>(queries, Wq, bq, Qw);
  proj_gemm<<<dim3(128, 8), 256, 0, stream>>>(keys, Wk, bk, Kw);
  proj_gemm<<<dim3(128, 8), 256, 0, stream>>>(values, Wv, bv, Vw);
  sample_scores<<<dim3(16, 64), 256, 0, stream>>>(Qw, Kw, samp, Mws);
  topk40<<<64, 256, 0, stream>>>(Mws, Mtop);
  init_out<<<4096, 256, 0, stream>>>(bo, out);
  flash_attn<<<dim3(SPLIT, 64), 256, 0, stream>>>(Qw, Kw, Vw, Mtop, ctxp, mlp);
  combine_ctx<<<64, 256, 0, stream>>>(ctxp, mlp, ctxf);
  scatter_out<<<2560, 256, 0, stream>>>(ctxf, Mtop, WoT, out);
}

// Round 2
// 1383.628 us; speedup vs baseline: 1.5448x; 1.5448x over previous
//
#include <hip/hip_runtime.h>

// ProbSparse attention, round 2: projections moved to MFMA via split-bf16
// (hi/lo, 3 passes: Xh*Wh + Xl*Wh + Xh*Wl). Attention path unchanged from R1.
// B=4, L=S=4096, D_MODEL=1024, H=16, D_K=64, SAMPLE_K=N_TOP=40, SCALE=1/8.

#define NTOP 40
#define NSAMP 40
#define SCALE 0.125f
#define SPLIT 16
#define KEYS_PER_SPLIT 256   // 4096 / SPLIT

// workspace offsets (in floats)
#define Q_OFF    0ull
#define K_OFF    16777216ull
#define V_OFF    33554432ull
#define M_OFF    50331648ull   // 262144 floats
#define MTOP_OFF 50593792ull   // 2560 ints (reserve 4096)
#define WOT_OFF  50597888ull   // 1048576 floats
#define CTXP_OFF 51646464ull   // 16*64*64*64 = 4194304 floats (also W hi/lo early)
#define MLP_OFF  55840768ull   // 16*64*64*2  = 131072 floats
#define CTX_OFF  55971840ull   // 64*40*64    = 163840 floats
// total = 56135680 floats = 224.5 MB of d_ws (same as R1)

typedef __attribute__((ext_vector_type(8))) short short8;
typedef __attribute__((ext_vector_type(4))) float floatx4;

// ---------------------------------------------------------------- bf16 split
__device__ inline unsigned short bf16_rne(float f) {
  unsigned u = __float_as_uint(f);
  unsigned r = (u + 0x7fffu + ((u >> 16) & 1u)) >> 16;
  return (unsigned short)r;
}

// x (fp32, n4*4 elems) -> hi bf16, lo bf16 (lo = rne(x - float(hi)))
__global__ __launch_bounds__(256) void split_bf16(
    const float* __restrict__ x, unsigned short* __restrict__ hi,
    unsigned short* __restrict__ lo, int n4) {
  int i = blockIdx.x * 256 + threadIdx.x;
  if (i >= n4) return;
  float4 v = ((const float4*)x)[i];
  ushort4 h, l;
  {
    h.x = bf16_rne(v.x);
    float hf = __uint_as_float((unsigned)h.x << 16);
    l.x = bf16_rne(v.x - hf);
  }
  {
    h.y = bf16_rne(v.y);
    float hf = __uint_as_float((unsigned)h.y << 16);
    l.y = bf16_rne(v.y - hf);
  }
  {
    h.z = bf16_rne(v.z);
    float hf = __uint_as_float((unsigned)h.z << 16);
    l.z = bf16_rne(v.z - hf);
  }
  {
    h.w = bf16_rne(v.w);
    float hf = __uint_as_float((unsigned)h.w << 16);
    l.w = bf16_rne(v.w - hf);
  }
  ((ushort4*)hi)[i] = h;
  ((ushort4*)lo)[i] = l;
}

// ---------------------------------------------------------------- async copy
__device__ inline void gl_lds16(const void* g, void* l) {
  __builtin_amdgcn_global_load_lds(
      (const __attribute__((address_space(1))) void*)g,
      (__attribute__((address_space(3))) void*)l, 16, 0, 0);
}

// ---------------------------------------------------------------- MFMA GEMM
// C[m][n] = sum_k X[m][k]*W[n][k] + bias[n]; M=16384, N=K=1024.
// 3 bf16 passes (Xh*Wh, Xl*Wh, Xh*Wl), fp32 MFMA accumulate.
// 128x128 tile, BK=32, 256 thr (4 waves, each a 64x64 quadrant of 16x16 tiles).
// m97 structure: global_load_lds(16B) staging, ds_read_b128 fragments.
// Output permuted to [b*16+h][l][64].
__global__ __launch_bounds__(256) void proj_gemm_mfma(
    const unsigned short* __restrict__ Xh, const unsigned short* __restrict__ Xl,
    const unsigned short* __restrict__ Wh, const unsigned short* __restrict__ Wl,
    const float* __restrict__ bias, float* __restrict__ Out) {
  __shared__ unsigned short As[128 * 32];  // [row m][k] row-major, unpadded
  __shared__ unsigned short Bs[128 * 32];  // [row n][k] row-major, unpadded
  const int t = threadIdx.x;
  const int lane = t & 63;
  const int w = t >> 6;
  const int m0 = blockIdx.x * 128;
  const int n0 = blockIdx.y * 128;

  // staging map: thread t covers tile bytes [t*16, t*16+16) per instruction
  const int sr = t >> 2;         // row 0..63 within half-tile
  const int sc = (t & 3) * 8;    // k-octet start
  char* AsB = (char*)As;
  char* BsB = (char*)Bs;
  const int ldsW = w * 1024;     // wave-uniform LDS byte base (lane*16 added by HW)

  // fragment map (16x16x32 bf16): A: m=lane&15,k=(lane>>4)*8+j ; B: n=lane&15,same k
  const int frow = lane & 15;
  const int koct = lane >> 4;
  const int m_off = (w & 1) * 64;
  const int n_off = (w >> 1) * 64;

  floatx4 acc[4][4] = {};

  const unsigned short* Asrc[3] = {Xh, Xl, Xh};
  const unsigned short* Bsrc[3] = {Wh, Wh, Wl};

  for (int pass = 0; pass < 3; ++pass) {
    const unsigned short* Ap = Asrc[pass];
    const unsigned short* Bp = Bsrc[pass];
    for (int k0 = 0; k0 < 1024; k0 += 32) {
      __syncthreads();  // prior compute done before LDS overwrite
      gl_lds16(&Ap[(size_t)(m0 + sr) * 1024 + k0 + sc], AsB + ldsW);
      gl_lds16(&Ap[(size_t)(m0 + 64 + sr) * 1024 + k0 + sc], AsB + 4096 + ldsW);
      gl_lds16(&Bp[(size_t)(n0 + sr) * 1024 + k0 + sc], BsB + ldsW);
      gl_lds16(&Bp[(size_t)(n0 + 64 + sr) * 1024 + k0 + sc], BsB + 4096 + ldsW);
      __syncthreads();  // drains vmcnt(0): tiles resident
      short8 af[4], bf[4];
#pragma unroll
      for (int mt = 0; mt < 4; ++mt)
        af[mt] = *(const short8*)(AsB + ((m_off + mt * 16 + frow) * 32 + koct * 8) * 2);
#pragma unroll
      for (int nt = 0; nt < 4; ++nt)
        bf[nt] = *(const short8*)(BsB + ((n_off + nt * 16 + frow) * 32 + koct * 8) * 2);
#pragma unroll
      for (int mt = 0; mt < 4; ++mt)
#pragma unroll
        for (int nt = 0; nt < 4; ++nt)
          acc[mt][nt] = __builtin_amdgcn_mfma_f32_16x16x32_bf16(
              af[mt], bf[nt], acc[mt][nt], 0, 0, 0);
    }
  }

  // epilogue: C/D layout m=(lane>>4)*4+reg, n=lane&15 (m89-verified)
#pragma unroll
  for (int nt = 0; nt < 4; ++nt) {
    const int n_g = n0 + n_off + nt * 16 + frow;
    const float bv = bias[n_g];
    const int h = n_g >> 6, d = n_g & 63;
#pragma unroll
    for (int mt = 0; mt < 4; ++mt) {
#pragma unroll
      for (int r = 0; r < 4; ++r) {
        const int m_g = m0 + m_off + mt * 16 + koct * 4 + r;
        const int b = m_g >> 12, l = m_g & 4095;
        Out[(((size_t)(b * 16 + h)) * 4096 + l) * 64 + d] = acc[mt][nt][r] + bv;
      }
    }
  }
}

// ---------------------------------------------------------------- transpose
__global__ __launch_bounds__(256) void transpose1024(
    const float* __restrict__ A, float* __restrict__ AT) {
  __shared__ float tile[64][68];
  const int t = threadIdx.x;
  const int x0 = blockIdx.x * 64;
  const int y0 = blockIdx.y * 64;
  const int tr = t >> 4;
  const int tc = (t & 15) * 4;
#pragma unroll
  for (int i = 0; i < 4; ++i) {
    int r = tr + i * 16;
    float4 v = *(const float4*)&A[(size_t)(y0 + r) * 1024 + x0 + tc];
    *(float4*)&tile[r][tc] = v;
  }
  __syncthreads();
#pragma unroll
  for (int i = 0; i < 4; ++i) {
    int r = tr + i * 16;
    float4 v;
    v.x = tile[tc + 0][r];
    v.y = tile[tc + 1][r];
    v.z = tile[tc + 2][r];
    v.w = tile[tc + 3][r];
    *(float4*)&AT[(size_t)(x0 + r) * 1024 + y0 + tc] = v;
  }
}

// ---------------------------------------------------------------- sample scores
__global__ __launch_bounds__(256) void sample_scores(
    const float* __restrict__ Q, const float* __restrict__ K,
    const int* __restrict__ samp, float* __restrict__ M) {
  __shared__ float Ks[NSAMP * 64];
  const int bh = blockIdx.y;
  const int t = threadIdx.x;
#pragma unroll
  for (int i = 0; i < 10; ++i) {
    int e = i * 256 + t;
    int s = e >> 6, d = e & 63;
    Ks[e] = K[((size_t)bh * 4096 + samp[s]) * 64 + d];
  }
  __syncthreads();
  const int l = blockIdx.x * 256 + t;
  const float* qp = &Q[((size_t)bh * 4096 + l) * 64];
  float4 q[16];
#pragma unroll
  for (int i = 0; i < 16; ++i) q[i] = *(const float4*)&qp[i * 4];
  float mx = -1e30f, sum = 0.f;
#pragma unroll
  for (int s = 0; s < NSAMP; ++s) {
    float acc = 0.f;
#pragma unroll
    for (int i = 0; i < 16; ++i) {
      float4 kv = *(const float4*)&Ks[s * 64 + i * 4];
      acc = fmaf(q[i].x, kv.x, acc);
      acc = fmaf(q[i].y, kv.y, acc);
      acc = fmaf(q[i].z, kv.z, acc);
      acc = fmaf(q[i].w, kv.w, acc);
    }
    mx = fmaxf(mx, acc);
    sum += acc;
  }
  M[(size_t)bh * 4096 + l] = mx - sum * (1.f / 40.f);
}

// ---------------------------------------------------------------- top-40
__global__ __launch_bounds__(256) void topk40(
    const float* __restrict__ M, int* __restrict__ Mtop) {
  __shared__ unsigned long long keys[4096];
  __shared__ unsigned long long red[256];
  const int bh = blockIdx.x;
  const int t = threadIdx.x;
#pragma unroll
  for (int i = 0; i < 16; ++i) {
    int idx = i * 256 + t;
    float f = M[(size_t)bh * 4096 + idx];
    unsigned int u = __float_as_uint(f);
    u = (u & 0x80000000u) ? ~u : (u | 0x80000000u);
    keys[idx] = (((unsigned long long)u) << 32) | (unsigned long long)(4095 - idx);
  }
  __syncthreads();
  for (int it = 0; it < NTOP; ++it) {
    unsigned long long best = 0;
#pragma unroll
    for (int i = 0; i < 16; ++i) {
      unsigned long long v = keys[i * 256 + t];
      best = v > best ? v : best;
    }
    red[t] = best;
    __syncthreads();
    for (int s = 128; s > 0; s >>= 1) {
      if (t < s) {
        unsigned long long o = red[t + s];
        if (o > red[t]) red[t] = o;
      }
      __syncthreads();
    }
    int idx = 4095 - (int)(red[0] & 0xFFFFFFFFull);
    if (t == 0) {
      Mtop[bh * NTOP + it] = idx;
      keys[idx] = 0;
    }
    __syncthreads();
  }
}

// ---------------------------------------------------------------- bias init
__global__ __launch_bounds__(256) void init_out(
    const float* __restrict__ bo, float* __restrict__ out) {
  const int t = threadIdx.x;
  const float4* bo4 = (const float4*)bo;
  float4* o4 = (float4*)out;
#pragma unroll
  for (int rep = 0; rep < 4; ++rep) {
    size_t idx = (size_t)rep * 1048576 + (size_t)blockIdx.x * 256 + t;
    o4[idx] = bo4[idx & 255];
  }
}

// ---------------------------------------------------------------- flash attention
__global__ __launch_bounds__(256) void flash_attn(
    const float* __restrict__ Q, const float* __restrict__ K,
    const float* __restrict__ V, const int* __restrict__ Mtop,
    float* __restrict__ ctx_part, float* __restrict__ ml_part) {
  __shared__ float Qs[64 * 64];
  __shared__ float Sb[64 * 65];
  __shared__ int topIdx[64];
  const int t = threadIdx.x;
  const int lane = t & 63;
  const int w = t >> 6;
  const int split = blockIdx.x;
  const int bh = blockIdx.y;
  if (t < 64) topIdx[t] = (t < NTOP) ? Mtop[bh * NTOP + t] : 0;
  __syncthreads();
#pragma unroll
  for (int i = 0; i < 4; ++i) {
    int e = i * 1024 + t * 4;
    int r = e >> 6, d = e & 63;
    float4 val = make_float4(0.f, 0.f, 0.f, 0.f);
    if (r < NTOP)
      val = *(const float4*)&Q[(((size_t)bh) * 4096 + topIdx[r]) * 64 + d];
    *(float4*)&Qs[e] = val;
  }
  float m_r = -1e30f, l_r = 0.f;
  float4 acc0 = make_float4(0.f, 0.f, 0.f, 0.f);
  float4 acc1 = acc0, acc2 = acc0, acc3 = acc0;
  const float* Kb = K + (size_t)bh * 4096 * 64;
  const float* Vb = V + (size_t)bh * 4096 * 64;
  const int key0 = split * KEYS_PER_SPLIT;
  const int d0 = w * 16;
  __syncthreads();

  for (int c = 0; c < KEYS_PER_SPLIT / 64; ++c) {
    const int j = key0 + c * 64 + lane;
    float4 kr[16];
#pragma unroll
    for (int i = 0; i < 16; ++i)
      kr[i] = *(const float4*)&Kb[(size_t)j * 64 + i * 4];
    const int rbase = w * 16;
#pragma unroll
    for (int rr = 0; rr < 16; ++rr) {
      const float* qrow = &Qs[(rbase + rr) * 64];
      float s = 0.f;
#pragma unroll
      for (int i = 0; i < 16; ++i) {
        float4 q4 = *(const float4*)&qrow[i * 4];
        s = fmaf(q4.x, kr[i].x, s);
        s = fmaf(q4.y, kr[i].y, s);
        s = fmaf(q4.z, kr[i].z, s);
        s = fmaf(q4.w, kr[i].w, s);
      }
      Sb[lane * 65 + rbase + rr] = s * SCALE;
    }
    __syncthreads();
    float sv[64];
    float cm = -1e30f;
#pragma unroll
    for (int j2 = 0; j2 < 64; ++j2) {
      sv[j2] = Sb[j2 * 65 + lane];
      cm = fmaxf(cm, sv[j2]);
    }
    float nm = fmaxf(m_r, cm);
    float alpha = __expf(m_r - nm);
    m_r = nm;
    l_r *= alpha;
    acc0.x *= alpha; acc0.y *= alpha; acc0.z *= alpha; acc0.w *= alpha;
    acc1.x *= alpha; acc1.y *= alpha; acc1.z *= alpha; acc1.w *= alpha;
    acc2.x *= alpha; acc2.y *= alpha; acc2.z *= alpha; acc2.w *= alpha;
    acc3.x *= alpha; acc3.y *= alpha; acc3.z *= alpha; acc3.w *= alpha;
#pragma unroll
    for (int j2 = 0; j2 < 64; ++j2) {
      float p = __expf(sv[j2] - nm);
      l_r += p;
      const float* vrow = &Vb[(size_t)(key0 + c * 64 + j2) * 64 + d0];
      float4 v0 = *(const float4*)&vrow[0];
      float4 v1 = *(const float4*)&vrow[4];
      float4 v2 = *(const float4*)&vrow[8];
      float4 v3 = *(const float4*)&vrow[12];
      acc0.x = fmaf(p, v0.x, acc0.x); acc0.y = fmaf(p, v0.y, acc0.y);
      acc0.z = fmaf(p, v0.z, acc0.z); acc0.w = fmaf(p, v0.w, acc0.w);
      acc1.x = fmaf(p, v1.x, acc1.x); acc1.y = fmaf(p, v1.y, acc1.y);
      acc1.z = fmaf(p, v1.z, acc1.z); acc1.w = fmaf(p, v1.w, acc1.w);
      acc2.x = fmaf(p, v2.x, acc2.x); acc2.y = fmaf(p, v2.y, acc2.y);
      acc2.z = fmaf(p, v2.z, acc2.z); acc2.w = fmaf(p, v2.w, acc2.w);
      acc3.x = fmaf(p, v3.x, acc3.x); acc3.y = fmaf(p, v3.y, acc3.y);
      acc3.z = fmaf(p, v3.z, acc3.z); acc3.w = fmaf(p, v3.w, acc3.w);
    }
    __syncthreads();
  }
  size_t pbase = (((size_t)split * 64 + bh) * 64 + lane) * 64 + d0;
  *(float4*)&ctx_part[pbase + 0] = acc0;
  *(float4*)&ctx_part[pbase + 4] = acc1;
  *(float4*)&ctx_part[pbase + 8] = acc2;
  *(float4*)&ctx_part[pbase + 12] = acc3;
  if (w == 0) {
    size_t mb = (((size_t)split * 64 + bh) * 64 + lane) * 2;
    ml_part[mb + 0] = m_r;
    ml_part[mb + 1] = l_r;
  }
}

// ---------------------------------------------------------------- combine splits
__global__ __launch_bounds__(256) void combine_ctx(
    const float* __restrict__ ctx_part, const float* __restrict__ ml_part,
    float* __restrict__ ctx) {
  const int bh = blockIdx.x;
  const int t = threadIdx.x;
  const int r = t & 63;
  const int dg = t >> 6;
  if (r >= NTOP) return;
  float mt = -1e30f;
#pragma unroll
  for (int s = 0; s < SPLIT; ++s)
    mt = fmaxf(mt, ml_part[(((size_t)s * 64 + bh) * 64 + r) * 2]);
  float Lt = 0.f;
  float4 a0 = make_float4(0.f, 0.f, 0.f, 0.f);
  float4 a1 = a0, a2 = a0, a3 = a0;
  const int d0 = dg * 16;
#pragma unroll
  for (int s = 0; s < SPLIT; ++s) {
    size_t mb = (((size_t)s * 64 + bh) * 64 + r) * 2;
    float ms = ml_part[mb], ls = ml_part[mb + 1];
    float wgt = __expf(ms - mt);
    Lt = fmaf(wgt, ls, Lt);
    size_t pb = (((size_t)s * 64 + bh) * 64 + r) * 64 + d0;
    float4 c0 = *(const float4*)&ctx_part[pb + 0];
    float4 c1 = *(const float4*)&ctx_part[pb + 4];
    float4 c2 = *(const float4*)&ctx_part[pb + 8];
    float4 c3 = *(const float4*)&ctx_part[pb + 12];
    a0.x = fmaf(wgt, c0.x, a0.x); a0.y = fmaf(wgt, c0.y, a0.y);
    a0.z = fmaf(wgt, c0.z, a0.z); a0.w = fmaf(wgt, c0.w, a0.w);
    a1.x = fmaf(wgt, c1.x, a1.x); a1.y = fmaf(wgt, c1.y, a1.y);
    a1.z = fmaf(wgt, c1.z, a1.z); a1.w = fmaf(wgt, c1.w, a1.w);
    a2.x = fmaf(wgt, c2.x, a2.x); a2.y = fmaf(wgt, c2.y, a2.y);
    a2.z = fmaf(wgt, c2.z, a2.z); a2.w = fmaf(wgt, c2.w, a2.w);
    a3.x = fmaf(wgt, c3.x, a3.x); a3.y = fmaf(wgt, c3.y, a3.y);
    a3.z = fmaf(wgt, c3.z, a3.z); a3.w = fmaf(wgt, c3.w, a3.w);
  }
  float inv = 1.f / Lt;
  size_t ob = ((size_t)bh * NTOP + r) * 64 + d0;
  a0.x *= inv; a0.y *= inv; a0.z *= inv; a0.w *= inv;
  a1.x *= inv; a1.y *= inv; a1.z *= inv; a1.w *= inv;
  a2.x *= inv; a2.y *= inv; a2.z *= inv; a2.w *= inv;
  a3.x *= inv; a3.y *= inv; a3.z *= inv; a3.w *= inv;
  *(float4*)&ctx[ob + 0] = a0;
  *(float4*)&ctx[ob + 4] = a1;
  *(float4*)&ctx[ob + 8] = a2;
  *(float4*)&ctx[ob + 12] = a3;
}

// ---------------------------------------------------------------- sparse out proj
__global__ __launch_bounds__(256) void scatter_out(
    const float* __restrict__ ctx, const int* __restrict__ Mtop,
    const float* __restrict__ WoT, float* __restrict__ out) {
  const int bx = blockIdx.x;
  const int bh = bx / NTOP;
  const int r = bx % NTOP;
  const int b = bh >> 4, h = bh & 15;
  const int t = threadIdx.x;
  __shared__ float crow[64];
  if (t < 16)
    *(float4*)&crow[t * 4] =
        *(const float4*)&ctx[((size_t)bh * NTOP + r) * 64 + t * 4];
  const int l = Mtop[bh * NTOP + r];
  __syncthreads();
  const int n0 = t * 4;
  float4 a = make_float4(0.f, 0.f, 0.f, 0.f);
#pragma unroll
  for (int d = 0; d < 64; ++d) {
    float cv = crow[d];
    float4 wv = *(const float4*)&WoT[(size_t)(h * 64 + d) * 1024 + n0];
    a.x = fmaf(cv, wv.x, a.x);
    a.y = fmaf(cv, wv.y, a.y);
    a.z = fmaf(cv, wv.z, a.z);
    a.w = fmaf(cv, wv.w, a.w);
  }
  float* orow = out + ((size_t)b * 4096 + l) * 1024 + n0;
  atomicAdd(&orow[0], a.x);
  atomicAdd(&orow[1], a.y);
  atomicAdd(&orow[2], a.z);
  atomicAdd(&orow[3], a.w);
}

// ---------------------------------------------------------------- launch
extern "C" void kernel_launch(void* const* d_in, const int* in_sizes, int n_in,
                              void* d_out, int out_size, void* d_ws, size_t ws_size,
                              hipStream_t stream) {
  const float* queries = (const float*)d_in[0];
  const float* keys    = (const float*)d_in[1];
  const float* values  = (const float*)d_in[2];
  const float* Wq = (const float*)d_in[3];
  const float* bq = (const float*)d_in[4];
  const float* Wk = (const float*)d_in[5];
  const float* bk = (const float*)d_in[6];
  const float* Wv = (const float*)d_in[7];
  const float* bv = (const float*)d_in[8];
  const float* Wo = (const float*)d_in[9];
  const float* bo = (const float*)d_in[10];
  const int* samp = (const int*)d_in[11];
  float* out = (float*)d_out;
  float* ws = (float*)d_ws;

  float* Qw   = ws + Q_OFF;
  float* Kw   = ws + K_OFF;
  float* Vw   = ws + V_OFF;
  float* Mws  = ws + M_OFF;
  int*   Mtop = (int*)(ws + MTOP_OFF);
  float* WoT  = ws + WOT_OFF;
  float* ctxp = ws + CTXP_OFF;
  float* mlp  = ws + MLP_OFF;
  float* ctxf = ws + CTX_OFF;

  // scratch reuse (serial stream => no hazards):
  //  - activation hi/lo (64 MB) lives in d_out until init_out overwrites it
  //  - weight hi/lo (4 MB) lives in ctxp region until flash_attn overwrites it
  unsigned short* Xh = (unsigned short*)d_out;
  unsigned short* Xl = Xh + 16777216;
  unsigned short* Whi = (unsigned short*)(ws + CTXP_OFF);
  unsigned short* Wlo = Whi + 1048576;

  dim3 ggrid(128, 8);

  split_bf16<<<16384, 256, 0, stream>>>(queries, Xh, Xl, 4194304);
  split_bf16<<<1024, 256, 0, stream>>>(Wq, Whi, Wlo, 262144);
  proj_gemm_mfma<<<ggrid, 256, 0, stream>>>(Xh, Xl, Whi, Wlo, bq, Qw);

  split_bf16<<<16384, 256, 0, stream>>>(keys, Xh, Xl, 4194304);
  split_bf16<<<1024, 256, 0, stream>>>(Wk, Whi, Wlo, 262144);
  proj_gemm_mfma<<<ggrid, 256, 0, stream>>>(Xh, Xl, Whi, Wlo, bk, Kw);

  split_bf16<<<16384, 256, 0, stream>>>(values, Xh, Xl, 4194304);
  split_bf16<<<1024, 256, 0, stream>>>(Wv, Whi, Wlo, 262144);
  proj_gemm_mfma<<<ggrid, 256, 0, stream>>>(Xh, Xl, Whi, Wlo, bv, Vw);

  transpose1024<<<dim3(16, 16), 256, 0, stream>>>(Wo, WoT);
  sample_scores<<<dim3(16, 64), 256, 0, stream>>>(Qw, Kw, samp, Mws);
  topk40<<<64, 256, 0, stream>>>(Mws, Mtop);
  init_out<<<4096, 256, 0, stream>>>(bo, out);
  flash_attn<<<dim3(SPLIT, 64), 256, 0, stream>>>(Qw, Kw, Vw, Mtop, ctxp, mlp);
  combine_ctx<<<64, 256, 0, stream>>>(ctxp, mlp, ctxf);
  scatter_out<<<2560, 256, 0, stream>>>(ctxf, Mtop, WoT, out);
}

// Round 4
// 953.332 us; speedup vs baseline: 2.2420x; 1.4514x over previous
//
#include <hip/hip_runtime.h>

// ProbSparse attention, round 4: R3 structure with the V-staging bug fixed —
// global_load_lds takes a PER-LANE global address; R3 passed a wave-uniform
// V address so all lanes fetched the same 16B. Now lane l fetches float4
// slot (slot0+l), matching its implicit LDS destination.
// B=4, L=S=4096, D_MODEL=1024, H=16, D_K=64, SAMPLE_K=N_TOP=40, SCALE=1/8.

#define NTOP 40
#define NSAMP 40
#define SCALE 0.125f
#define SPLIT 16
#define KEYS_PER_SPLIT 256   // 4096 / SPLIT
#define CHUNK 64
#define NCHUNK 4             // KEYS_PER_SPLIT / CHUNK

// workspace offsets (in floats)
#define Q_OFF    0ull
#define K_OFF    16777216ull
#define V_OFF    33554432ull
#define M_OFF    50331648ull   // 262144 floats
#define MTOP_OFF 50593792ull   // 2560 ints (reserve 4096)
#define WOT_OFF  50597888ull   // 1048576 floats
#define CTXP_OFF 51646464ull   // 16*64*64*64 = 4194304 floats (also W hi/lo early)
#define MLP_OFF  55840768ull   // 16*64*64*2  = 131072 floats
#define CTX_OFF  55971840ull   // 64*40*64    = 163840 floats
// total = 56135680 floats = 224.5 MB of d_ws

typedef __attribute__((ext_vector_type(8))) short short8;
typedef __attribute__((ext_vector_type(4))) float floatx4;

// ---------------------------------------------------------------- bf16 split
__device__ inline unsigned short bf16_rne(float f) {
  unsigned u = __float_as_uint(f);
  unsigned r = (u + 0x7fffu + ((u >> 16) & 1u)) >> 16;
  return (unsigned short)r;
}

__global__ __launch_bounds__(256) void split_bf16(
    const float* __restrict__ x, unsigned short* __restrict__ hi,
    unsigned short* __restrict__ lo, int n4) {
  int i = blockIdx.x * 256 + threadIdx.x;
  if (i >= n4) return;
  float4 v = ((const float4*)x)[i];
  ushort4 h, l;
  {
    h.x = bf16_rne(v.x);
    float hf = __uint_as_float((unsigned)h.x << 16);
    l.x = bf16_rne(v.x - hf);
  }
  {
    h.y = bf16_rne(v.y);
    float hf = __uint_as_float((unsigned)h.y << 16);
    l.y = bf16_rne(v.y - hf);
  }
  {
    h.z = bf16_rne(v.z);
    float hf = __uint_as_float((unsigned)h.z << 16);
    l.z = bf16_rne(v.z - hf);
  }
  {
    h.w = bf16_rne(v.w);
    float hf = __uint_as_float((unsigned)h.w << 16);
    l.w = bf16_rne(v.w - hf);
  }
  ((ushort4*)hi)[i] = h;
  ((ushort4*)lo)[i] = l;
}

// ---------------------------------------------------------------- async copy
__device__ inline void gl_lds16(const void* g, void* l) {
  __builtin_amdgcn_global_load_lds(
      (const __attribute__((address_space(1))) void*)g,
      (__attribute__((address_space(3))) void*)l, 16, 0, 0);
}

// ---------------------------------------------------------------- MFMA GEMM
__global__ __launch_bounds__(256) void proj_gemm_mfma(
    const unsigned short* __restrict__ Xh, const unsigned short* __restrict__ Xl,
    const unsigned short* __restrict__ Wh, const unsigned short* __restrict__ Wl,
    const float* __restrict__ bias, float* __restrict__ Out) {
  __shared__ unsigned short As[128 * 32];
  __shared__ unsigned short Bs[128 * 32];
  const int t = threadIdx.x;
  const int lane = t & 63;
  const int w = t >> 6;
  const int m0 = blockIdx.x * 128;
  const int n0 = blockIdx.y * 128;

  const int sr = t >> 2;
  const int sc = (t & 3) * 8;
  char* AsB = (char*)As;
  char* BsB = (char*)Bs;
  const int ldsW = w * 1024;

  const int frow = lane & 15;
  const int koct = lane >> 4;
  const int m_off = (w & 1) * 64;
  const int n_off = (w >> 1) * 64;

  floatx4 acc[4][4] = {};

  const unsigned short* Asrc[3] = {Xh, Xl, Xh};
  const unsigned short* Bsrc[3] = {Wh, Wh, Wl};

  for (int pass = 0; pass < 3; ++pass) {
    const unsigned short* Ap = Asrc[pass];
    const unsigned short* Bp = Bsrc[pass];
    for (int k0 = 0; k0 < 1024; k0 += 32) {
      __syncthreads();
      gl_lds16(&Ap[(size_t)(m0 + sr) * 1024 + k0 + sc], AsB + ldsW);
      gl_lds16(&Ap[(size_t)(m0 + 64 + sr) * 1024 + k0 + sc], AsB + 4096 + ldsW);
      gl_lds16(&Bp[(size_t)(n0 + sr) * 1024 + k0 + sc], BsB + ldsW);
      gl_lds16(&Bp[(size_t)(n0 + 64 + sr) * 1024 + k0 + sc], BsB + 4096 + ldsW);
      __syncthreads();
      short8 af[4], bf[4];
#pragma unroll
      for (int mt = 0; mt < 4; ++mt)
        af[mt] = *(const short8*)(AsB + ((m_off + mt * 16 + frow) * 32 + koct * 8) * 2);
#pragma unroll
      for (int nt = 0; nt < 4; ++nt)
        bf[nt] = *(const short8*)(BsB + ((n_off + nt * 16 + frow) * 32 + koct * 8) * 2);
#pragma unroll
      for (int mt = 0; mt < 4; ++mt)
#pragma unroll
        for (int nt = 0; nt < 4; ++nt)
          acc[mt][nt] = __builtin_amdgcn_mfma_f32_16x16x32_bf16(
              af[mt], bf[nt], acc[mt][nt], 0, 0, 0);
    }
  }

#pragma unroll
  for (int nt = 0; nt < 4; ++nt) {
    const int n_g = n0 + n_off + nt * 16 + frow;
    const float bv = bias[n_g];
    const int h = n_g >> 6, d = n_g & 63;
#pragma unroll
    for (int mt = 0; mt < 4; ++mt) {
#pragma unroll
      for (int r = 0; r < 4; ++r) {
        const int m_g = m0 + m_off + mt * 16 + koct * 4 + r;
        const int b = m_g >> 12, l = m_g & 4095;
        Out[(((size_t)(b * 16 + h)) * 4096 + l) * 64 + d] = acc[mt][nt][r] + bv;
      }
    }
  }
}

// ---------------------------------------------------------------- transpose
__global__ __launch_bounds__(256) void transpose1024(
    const float* __restrict__ A, float* __restrict__ AT) {
  __shared__ float tile[64][68];
  const int t = threadIdx.x;
  const int x0 = blockIdx.x * 64;
  const int y0 = blockIdx.y * 64;
  const int tr = t >> 4;
  const int tc = (t & 15) * 4;
#pragma unroll
  for (int i = 0; i < 4; ++i) {
    int r = tr + i * 16;
    float4 v = *(const float4*)&A[(size_t)(y0 + r) * 1024 + x0 + tc];
    *(float4*)&tile[r][tc] = v;
  }
  __syncthreads();
#pragma unroll
  for (int i = 0; i < 4; ++i) {
    int r = tr + i * 16;
    float4 v;
    v.x = tile[tc + 0][r];
    v.y = tile[tc + 1][r];
    v.z = tile[tc + 2][r];
    v.w = tile[tc + 3][r];
    *(float4*)&AT[(size_t)(x0 + r) * 1024 + y0 + tc] = v;
  }
}

// ---------------------------------------------------------------- sample scores
__global__ __launch_bounds__(256) void sample_scores(
    const float* __restrict__ Q, const float* __restrict__ K,
    const int* __restrict__ samp, float* __restrict__ M) {
  __shared__ float Ks[NSAMP * 64];
  const int bh = blockIdx.y;
  const int t = threadIdx.x;
#pragma unroll
  for (int i = 0; i < 10; ++i) {
    int e = i * 256 + t;
    int s = e >> 6, d = e & 63;
    Ks[e] = K[((size_t)bh * 4096 + samp[s]) * 64 + d];
  }
  __syncthreads();
  const int l = blockIdx.x * 256 + t;
  const float* qp = &Q[((size_t)bh * 4096 + l) * 64];
  float4 q[16];
#pragma unroll
  for (int i = 0; i < 16; ++i) q[i] = *(const float4*)&qp[i * 4];
  float mx = -1e30f, sum = 0.f;
#pragma unroll
  for (int s = 0; s < NSAMP; ++s) {
    float acc = 0.f;
#pragma unroll
    for (int i = 0; i < 16; ++i) {
      float4 kv = *(const float4*)&Ks[s * 64 + i * 4];
      acc = fmaf(q[i].x, kv.x, acc);
      acc = fmaf(q[i].y, kv.y, acc);
      acc = fmaf(q[i].z, kv.z, acc);
      acc = fmaf(q[i].w, kv.w, acc);
    }
    mx = fmaxf(mx, acc);
    sum += acc;
  }
  M[(size_t)bh * 4096 + l] = mx - sum * (1.f / 40.f);
}

// ---------------------------------------------------------------- top-40
__global__ __launch_bounds__(256) void topk40(
    const float* __restrict__ M, int* __restrict__ Mtop) {
  __shared__ unsigned long long keys[4096];
  __shared__ unsigned long long red[256];
  const int bh = blockIdx.x;
  const int t = threadIdx.x;
#pragma unroll
  for (int i = 0; i < 16; ++i) {
    int idx = i * 256 + t;
    float f = M[(size_t)bh * 4096 + idx];
    unsigned int u = __float_as_uint(f);
    u = (u & 0x80000000u) ? ~u : (u | 0x80000000u);
    keys[idx] = (((unsigned long long)u) << 32) | (unsigned long long)(4095 - idx);
  }
  __syncthreads();
  for (int it = 0; it < NTOP; ++it) {
    unsigned long long best = 0;
#pragma unroll
    for (int i = 0; i < 16; ++i) {
      unsigned long long v = keys[i * 256 + t];
      best = v > best ? v : best;
    }
    red[t] = best;
    __syncthreads();
    for (int s = 128; s > 0; s >>= 1) {
      if (t < s) {
        unsigned long long o = red[t + s];
        if (o > red[t]) red[t] = o;
      }
      __syncthreads();
    }
    int idx = 4095 - (int)(red[0] & 0xFFFFFFFFull);
    if (t == 0) {
      Mtop[bh * NTOP + it] = idx;
      keys[idx] = 0;
    }
    __syncthreads();
  }
}

// ---------------------------------------------------------------- bias init
__global__ __launch_bounds__(256) void init_out(
    const float* __restrict__ bo, float* __restrict__ out) {
  const int t = threadIdx.x;
  const float4* bo4 = (const float4*)bo;
  float4* o4 = (float4*)out;
#pragma unroll
  for (int rep = 0; rep < 4; ++rep) {
    size_t idx = (size_t)rep * 1048576 + (size_t)blockIdx.x * 256 + t;
    o4[idx] = bo4[idx & 255];
  }
}

// ---------------------------------------------------------------- flash attention
// grid (SPLIT, 64), 256 threads (4 waves). Per 64-key chunk:
//   stage K (swizzled: row j, slot s holds d4=(s-j)&15) + V (linear) via
//   global_load_lds(16B) — PER-LANE global addr, implicit LDS dest base+lane*16;
//   phase A: lane=key, wave w computes rows [10w,10w+10) -> Sb stride 41;
//   phase B: lane=row (40 active), wave owns d-slice of 16.
__global__ __launch_bounds__(256) void flash_attn(
    const float* __restrict__ Q, const float* __restrict__ K,
    const float* __restrict__ V, const int* __restrict__ Mtop,
    float* __restrict__ ctx_part, float* __restrict__ ml_part) {
  __shared__ float Qs[NTOP * 64];   // 10.0 KB
  __shared__ float Ks[64 * 64];     // 16 KB, swizzled
  __shared__ float Vs[64 * 64];     // 16 KB, linear
  __shared__ float Sb[64 * 41];     // 10.25 KB
  __shared__ int topIdx[NTOP];
  const int t = threadIdx.x;
  const int lane = t & 63;
  const int w = t >> 6;
  const int split = blockIdx.x;
  const int bh = blockIdx.y;

  if (t < NTOP) topIdx[t] = Mtop[bh * NTOP + t];
  __syncthreads();
  // stage Q tile: 640 float4 (40 rows x 16)
  for (int i = t; i < NTOP * 16; i += 256) {
    int r = i >> 4, c4 = i & 15;
    *(float4*)&Qs[r * 64 + c4 * 4] =
        *(const float4*)&Q[(((size_t)bh) * 4096 + topIdx[r]) * 64 + c4 * 4];
  }

  const float* Kb = K + (size_t)bh * 4096 * 64;
  const float* Vb = V + (size_t)bh * 4096 * 64;
  const int key0 = split * KEYS_PER_SPLIT;
  const int d0 = w * 16;
  const int s_in_row = lane & 15;
  const int lrow = lane >> 4;

  float m_r = -1e30f, l_r = 0.f;
  float4 acc0 = make_float4(0.f, 0.f, 0.f, 0.f);
  float4 acc1 = acc0, acc2 = acc0, acc3 = acc0;

  for (int c = 0; c < NCHUNK; ++c) {
    __syncthreads();  // prev phase B done (Q ready on c==0)
    const int jbase = key0 + c * CHUNK;
    // stage: 4 K insts + 4 V insts per wave; each covers 1 KB (4 rows)
#pragma unroll
    for (int n = 0; n < 4; ++n) {
      const int slot0 = n * 256 + w * 64;       // wave-uniform float4-slot base
      const int j = (slot0 >> 4) + lrow;        // this lane's K row
      const int d4 = (s_in_row - j) & 15;       // swizzled float4 within row
      gl_lds16(&Kb[(size_t)(jbase + j) * 64 + d4 * 4], (char*)Ks + slot0 * 16);
      // V: lane l supplies the global float4 (slot0+l); LDS dest = base+l*16
      gl_lds16(&Vb[(size_t)jbase * 64 + (size_t)(slot0 + lane) * 4],
               (char*)Vs + slot0 * 16);
    }
    __syncthreads();  // vmcnt drained -> K,V resident

    // ---- phase A: scores. lane = key, wave w covers rows [10w, 10w+10)
    float4 kr[16];
#pragma unroll
    for (int i = 0; i < 16; ++i)
      kr[i] = *(const float4*)&Ks[(lane * 16 + ((i + lane) & 15)) * 4];
#pragma unroll
    for (int rr = 0; rr < 10; ++rr) {
      const int r = w * 10 + rr;
      const float* qrow = &Qs[r * 64];
      float s = 0.f;
#pragma unroll
      for (int i = 0; i < 16; ++i) {
        float4 q4 = *(const float4*)&qrow[i * 4];
        s = fmaf(q4.x, kr[i].x, s);
        s = fmaf(q4.y, kr[i].y, s);
        s = fmaf(q4.z, kr[i].z, s);
        s = fmaf(q4.w, kr[i].w, s);
      }
      Sb[lane * 41 + r] = s * SCALE;
    }
    __syncthreads();  // Sb ready

    // ---- phase B: lane = row (40 active), wave w owns d-slice [16w,16w+16)
    if (lane < NTOP) {
      float sv[64];
      float cm = -1e30f;
#pragma unroll
      for (int j2 = 0; j2 < 64; ++j2) {
        sv[j2] = Sb[j2 * 41 + lane];
        cm = fmaxf(cm, sv[j2]);
      }
      const float nm = fmaxf(m_r, cm);
      const float alpha = __expf(m_r - nm);
      m_r = nm;
      l_r *= alpha;
      acc0.x *= alpha; acc0.y *= alpha; acc0.z *= alpha; acc0.w *= alpha;
      acc1.x *= alpha; acc1.y *= alpha; acc1.z *= alpha; acc1.w *= alpha;
      acc2.x *= alpha; acc2.y *= alpha; acc2.z *= alpha; acc2.w *= alpha;
      acc3.x *= alpha; acc3.y *= alpha; acc3.z *= alpha; acc3.w *= alpha;
#pragma unroll
      for (int j2 = 0; j2 < 64; ++j2) {
        const float p = __expf(sv[j2] - nm);
        l_r += p;
        const float* vrow = &Vs[j2 * 64 + d0];   // broadcast within wave
        float4 v0 = *(const float4*)&vrow[0];
        float4 v1 = *(const float4*)&vrow[4];
        float4 v2 = *(const float4*)&vrow[8];
        float4 v3 = *(const float4*)&vrow[12];
        acc0.x = fmaf(p, v0.x, acc0.x); acc0.y = fmaf(p, v0.y, acc0.y);
        acc0.z = fmaf(p, v0.z, acc0.z); acc0.w = fmaf(p, v0.w, acc0.w);
        acc1.x = fmaf(p, v1.x, acc1.x); acc1.y = fmaf(p, v1.y, acc1.y);
        acc1.z = fmaf(p, v1.z, acc1.z); acc1.w = fmaf(p, v1.w, acc1.w);
        acc2.x = fmaf(p, v2.x, acc2.x); acc2.y = fmaf(p, v2.y, acc2.y);
        acc2.z = fmaf(p, v2.z, acc2.z); acc2.w = fmaf(p, v2.w, acc2.w);
        acc3.x = fmaf(p, v3.x, acc3.x); acc3.y = fmaf(p, v3.y, acc3.y);
        acc3.z = fmaf(p, v3.z, acc3.z); acc3.w = fmaf(p, v3.w, acc3.w);
      }
    }
  }

  if (lane < NTOP) {
    size_t pbase = (((size_t)split * 64 + bh) * 64 + lane) * 64 + d0;
    *(float4*)&ctx_part[pbase + 0] = acc0;
    *(float4*)&ctx_part[pbase + 4] = acc1;
    *(float4*)&ctx_part[pbase + 8] = acc2;
    *(float4*)&ctx_part[pbase + 12] = acc3;
  }
  if (w == 0) {
    size_t mb = (((size_t)split * 64 + bh) * 64 + lane) * 2;
    ml_part[mb + 0] = m_r;
    ml_part[mb + 1] = l_r;
  }
}

// ---------------------------------------------------------------- combine splits
__global__ __launch_bounds__(256) void combine_ctx(
    const float* __restrict__ ctx_part, const float* __restrict__ ml_part,
    float* __restrict__ ctx) {
  const int bh = blockIdx.x;
  const int t = threadIdx.x;
  const int r = t & 63;
  const int dg = t >> 6;
  if (r >= NTOP) return;
  float mt = -1e30f;
#pragma unroll
  for (int s = 0; s < SPLIT; ++s)
    mt = fmaxf(mt, ml_part[(((size_t)s * 64 + bh) * 64 + r) * 2]);
  float Lt = 0.f;
  float4 a0 = make_float4(0.f, 0.f, 0.f, 0.f);
  float4 a1 = a0, a2 = a0, a3 = a0;
  const int d0 = dg * 16;
#pragma unroll
  for (int s = 0; s < SPLIT; ++s) {
    size_t mb = (((size_t)s * 64 + bh) * 64 + r) * 2;
    float ms = ml_part[mb], ls = ml_part[mb + 1];
    float wgt = __expf(ms - mt);
    Lt = fmaf(wgt, ls, Lt);
    size_t pb = (((size_t)s * 64 + bh) * 64 + r) * 64 + d0;
    float4 c0 = *(const float4*)&ctx_part[pb + 0];
    float4 c1 = *(const float4*)&ctx_part[pb + 4];
    float4 c2 = *(const float4*)&ctx_part[pb + 8];
    float4 c3 = *(const float4*)&ctx_part[pb + 12];
    a0.x = fmaf(wgt, c0.x, a0.x); a0.y = fmaf(wgt, c0.y, a0.y);
    a0.z = fmaf(wgt, c0.z, a0.z); a0.w = fmaf(wgt, c0.w, a0.w);
    a1.x = fmaf(wgt, c1.x, a1.x); a1.y = fmaf(wgt, c1.y, a1.y);
    a1.z = fmaf(wgt, c1.z, a1.z); a1.w = fmaf(wgt, c1.w, a1.w);
    a2.x = fmaf(wgt, c2.x, a2.x); a2.y = fmaf(wgt, c2.y, a2.y);
    a2.z = fmaf(wgt, c2.z, a2.z); a2.w = fmaf(wgt, c2.w, a2.w);
    a3.x = fmaf(wgt, c3.x, a3.x); a3.y = fmaf(wgt, c3.y, a3.y);
    a3.z = fmaf(wgt, c3.z, a3.z); a3.w = fmaf(wgt, c3.w, a3.w);
  }
  float inv = 1.f / Lt;
  size_t ob = ((size_t)bh * NTOP + r) * 64 + d0;
  a0.x *= inv; a0.y *= inv; a0.z *= inv; a0.w *= inv;
  a1.x *= inv; a1.y *= inv; a1.z *= inv; a1.w *= inv;
  a2.x *= inv; a2.y *= inv; a2.z *= inv; a2.w *= inv;
  a3.x *= inv; a3.y *= inv; a3.z *= inv; a3.w *= inv;
  *(float4*)&ctx[ob + 0] = a0;
  *(float4*)&ctx[ob + 4] = a1;
  *(float4*)&ctx[ob + 8] = a2;
  *(float4*)&ctx[ob + 12] = a3;
}

// ---------------------------------------------------------------- sparse out proj
__global__ __launch_bounds__(256) void scatter_out(
    const float* __restrict__ ctx, const int* __restrict__ Mtop,
    const float* __restrict__ WoT, float* __restrict__ out) {
  const int bx = blockIdx.x;
  const int bh = bx / NTOP;
  const int r = bx % NTOP;
  const int b = bh >> 4, h = bh & 15;
  const int t = threadIdx.x;
  __shared__ float crow[64];
  if (t < 16)
    *(float4*)&crow[t * 4] =
        *(const float4*)&ctx[((size_t)bh * NTOP + r) * 64 + t * 4];
  const int l = Mtop[bh * NTOP + r];
  __syncthreads();
  const int n0 = t * 4;
  float4 a = make_float4(0.f, 0.f, 0.f, 0.f);
#pragma unroll
  for (int d = 0; d < 64; ++d) {
    float cv = crow[d];
    float4 wv = *(const float4*)&WoT[(size_t)(h * 64 + d) * 1024 + n0];
    a.x = fmaf(cv, wv.x, a.x);
    a.y = fmaf(cv, wv.y, a.y);
    a.z = fmaf(cv, wv.z, a.z);
    a.w = fmaf(cv, wv.w, a.w);
  }
  float* orow = out + ((size_t)b * 4096 + l) * 1024 + n0;
  atomicAdd(&orow[0], a.x);
  atomicAdd(&orow[1], a.y);
  atomicAdd(&orow[2], a.z);
  atomicAdd(&orow[3], a.w);
}

// ---------------------------------------------------------------- launch
extern "C" void kernel_launch(void* const* d_in, const int* in_sizes, int n_in,
                              void* d_out, int out_size, void* d_ws, size_t ws_size,
                              hipStream_t stream) {
  const float* queries = (const float*)d_in[0];
  const float* keys    = (const float*)d_in[1];
  const float* values  = (const float*)d_in[2];
  const float* Wq = (const float*)d_in[3];
  const float* bq = (const float*)d_in[4];
  const float* Wk = (const float*)d_in[5];
  const float* bk = (const float*)d_in[6];
  const float* Wv = (const float*)d_in[7];
  const float* bv = (const float*)d_in[8];
  const float* Wo = (const float*)d_in[9];
  const float* bo = (const float*)d_in[10];
  const int* samp = (const int*)d_in[11];
  float* out = (float*)d_out;
  float* ws = (float*)d_ws;

  float* Qw   = ws + Q_OFF;
  float* Kw   = ws + K_OFF;
  float* Vw   = ws + V_OFF;
  float* Mws  = ws + M_OFF;
  int*   Mtop = (int*)(ws + MTOP_OFF);
  float* WoT  = ws + WOT_OFF;
  float* ctxp = ws + CTXP_OFF;
  float* mlp  = ws + MLP_OFF;
  float* ctxf = ws + CTX_OFF;

  unsigned short* Xh = (unsigned short*)d_out;
  unsigned short* Xl = Xh + 16777216;
  unsigned short* Whi = (unsigned short*)(ws + CTXP_OFF);
  unsigned short* Wlo = Whi + 1048576;

  dim3 ggrid(128, 8);

  split_bf16<<<16384, 256, 0, stream>>>(queries, Xh, Xl, 4194304);
  split_bf16<<<1024, 256, 0, stream>>>(Wq, Whi, Wlo, 262144);
  proj_gemm_mfma<<<ggrid, 256, 0, stream>>>(Xh, Xl, Whi, Wlo, bq, Qw);

  split_bf16<<<16384, 256, 0, stream>>>(keys, Xh, Xl, 4194304);
  split_bf16<<<1024, 256, 0, stream>>>(Wk, Whi, Wlo, 262144);
  proj_gemm_mfma<<<ggrid, 256, 0, stream>>>(Xh, Xl, Whi, Wlo, bk, Kw);

  split_bf16<<<16384, 256, 0, stream>>>(values, Xh, Xl, 4194304);
  split_bf16<<<1024, 256, 0, stream>>>(Wv, Whi, Wlo, 262144);
  proj_gemm_mfma<<<ggrid, 256, 0, stream>>>(Xh, Xl, Whi, Wlo, bv, Vw);

  transpose1024<<<dim3(16, 16), 256, 0, stream>>>(Wo, WoT);
  sample_scores<<<dim3(16, 64), 256, 0, stream>>>(Qw, Kw, samp, Mws);
  topk40<<<64, 256, 0, stream>>>(Mws, Mtop);
  init_out<<<4096, 256, 0, stream>>>(bo, out);
  flash_attn<<<dim3(SPLIT, 64), 256, 0, stream>>>(Qw, Kw, Vw, Mtop, ctxp, mlp);
  combine_ctx<<<64, 256, 0, stream>>>(ctxp, mlp, ctxf);
  scatter_out<<<2560, 256, 0, stream>>>(ctxf, Mtop, WoT, out);
}